// Round 1
// baseline (4634.695 us; speedup 1.0000x reference)
//
#include <hip/hip_runtime.h>
#include <math.h>

#define V_WORDS 20000
#define MM 32
#define EE 128
#define HH 4
#define DHH 32
#define NN 8192
#define LL 64
#define CC 128

// ---------------------------------------------------------------------------
// Kernel 1: word embeddings (masked mean query + 1-query MHA + out proj)
// one block per word, 256 threads
// ---------------------------------------------------------------------------
__global__ __launch_bounds__(256)
void word_embed_kernel(const int* __restrict__ word2news,
                       const int* __restrict__ word2news_len,
                       const float* __restrict__ table,
                       const float* __restrict__ in_w,
                       const float* __restrict__ in_b,
                       const float* __restrict__ out_w,
                       const float* __restrict__ out_b,
                       float* __restrict__ we)
{
    const int v = blockIdx.x;
    const int t = threadIdx.x;
    const int len = word2news_len[v];
    if (len <= 0) {                       // reference zeroes words with no news
        if (t < EE) we[v * EE + t] = 0.0f;
        return;
    }

    __shared__ float ctx[MM][EE];
    __shared__ float khs[MM][EE];
    __shared__ float vhs[MM][EE];
    __shared__ float qs[EE];
    __shared__ float qhs[EE];
    __shared__ float attn[HH][MM];
    __shared__ float osh[EE];
    __shared__ int rows[MM];

    const int e = t & (EE - 1);
    const int hpart = t >> 7;             // 0 or 1

    if (t < MM) rows[t] = word2news[v * MM + t];
    __syncthreads();

    // gather context rows; zero-fill m >= len so later sums are branch-free
    for (int m = hpart; m < MM; m += 2) {
        float val = 0.0f;
        if (m < len) val = table[rows[m] * EE + e];
        ctx[m][e] = val;
    }
    __syncthreads();

    // masked mean query
    if (t < EE) {
        float s = 0.0f;
        #pragma unroll
        for (int m = 0; m < MM; ++m) s += ctx[m][t];
        qs[t] = s / (float)len;
    }
    __syncthreads();

    // q projection (threads 0..127)
    if (t < EE) {
        float acc = in_b[t];
        const float* wq = in_w + t * EE;
        for (int k = 0; k < EE; ++k) acc += qs[k] * wq[k];
        qhs[t] = acc;
    }

    // k projection (threads 0..127) and v projection (threads 128..255),
    // 16-row register blocks so each w row is read only twice per block
    {
        const int i = e;
        const float* w = in_w + (hpart == 0 ? EE * EE : 2 * EE * EE) + i * EE;
        const float bias = in_b[(hpart == 0 ? EE : 2 * EE) + i];
        float (*dst)[EE] = (hpart == 0) ? khs : vhs;

        float acc[16];
        #pragma unroll
        for (int m = 0; m < 16; ++m) acc[m] = bias;
        for (int k = 0; k < EE; ++k) {
            const float wv = w[k];
            #pragma unroll
            for (int m = 0; m < 16; ++m) acc[m] += ctx[m][k] * wv;
        }
        #pragma unroll
        for (int m = 0; m < 16; ++m) dst[m][i] = acc[m];

        if (len > 16) {
            #pragma unroll
            for (int m = 0; m < 16; ++m) acc[m] = bias;
            for (int k = 0; k < EE; ++k) {
                const float wv = w[k];
                #pragma unroll
                for (int m = 0; m < 16; ++m) acc[m] += ctx[16 + m][k] * wv;
            }
            #pragma unroll
            for (int m = 0; m < 16; ++m) dst[16 + m][i] = acc[m];
        } else {
            // rows 16..31 never contribute (attn==0 there) but must be finite
            #pragma unroll
            for (int m = 16; m < MM; ++m) dst[m][i] = 0.0f;
        }
    }
    __syncthreads();

    // scores + softmax: threads 0..127, one (head, m) pair each
    if (t < HH * MM) {
        const int h = t >> 5, m = t & 31;
        float s;
        if (m < len) {
            float d = 0.0f;
            #pragma unroll
            for (int dd = 0; dd < DHH; ++dd)
                d += qhs[h * DHH + dd] * khs[m][h * DHH + dd];
            s = d * 0.17677669529663687f;   // 1/sqrt(Dh)
        } else {
            s = -1e9f;                       // reference mask value
        }
        float mx = s;
        #pragma unroll
        for (int off = 16; off > 0; off >>= 1)
            mx = fmaxf(mx, __shfl_xor(mx, off, 32));
        const float ex = expf(s - mx);       // masked lanes underflow to 0
        float sum = ex;
        #pragma unroll
        for (int off = 16; off > 0; off >>= 1)
            sum += __shfl_xor(sum, off, 32);
        attn[h][m] = ex / sum;
    }
    __syncthreads();

    // attention-weighted value sum
    if (t < EE) {
        const int h = t >> 5;               // head of channel t
        float acc = 0.0f;
        #pragma unroll
        for (int m = 0; m < MM; ++m) acc += attn[h][m] * vhs[m][t];
        osh[t] = acc;
    }
    __syncthreads();

    // output projection
    if (t < EE) {
        float acc = out_b[t];
        const float* wr = out_w + t * EE;
        for (int k = 0; k < EE; ++k) acc += osh[k] * wr[k];
        we[v * EE + t] = acc;
    }
}

// ---------------------------------------------------------------------------
// Kernel 2: gather doc -> conv(3,4,5) + relu + maxpool -> fc
// one block per news item, 256 threads = 128 channels x 2 position halves
// ---------------------------------------------------------------------------
template<int K>
__device__ __forceinline__ void conv_one(const float (&docT)[EE][LL + 2],
                                         const float* __restrict__ w,
                                         const float* __restrict__ b,
                                         int c, int half,
                                         float* __restrict__ feat /* LDS, CC */)
{
    const int NP = LL - K + 1;
    const int P0 = half * 31;
    float acc[31];
    #pragma unroll
    for (int p = 0; p < 31; ++p) acc[p] = 0.0f;

    const float* wr = w + c * (EE * K);
    for (int ee = 0; ee < EE; ++ee) {
        float d[31 + K - 1];                 // contiguous LDS row chunk
        #pragma unroll
        for (int i = 0; i < 31 + K - 1; ++i) d[i] = docT[ee][P0 + i];
        #pragma unroll
        for (int j = 0; j < K; ++j) {
            const float wv = wr[ee * K + j];
            #pragma unroll
            for (int p = 0; p < 31; ++p) acc[p] += d[p + j] * wv;
        }
    }

    const float bias = b[c];
    const int cnt = min(31, NP - P0);        // valid positions in this half
    float mx = 0.0f;                         // relu output is >= 0
    #pragma unroll
    for (int p = 0; p < 31; ++p) {
        const float y = fmaxf(acc[p] + bias, 0.0f);
        if (p < cnt) mx = fmaxf(mx, y);
    }
    if (half == 0) feat[c] = mx;
    __syncthreads();
    if (half == 1) feat[c] = fmaxf(feat[c], mx);
    __syncthreads();
}

__global__ __launch_bounds__(256)
void news_kernel(const int* __restrict__ news_words,
                 const float* __restrict__ we,
                 const float* __restrict__ w3, const float* __restrict__ b3,
                 const float* __restrict__ w4, const float* __restrict__ b4,
                 const float* __restrict__ w5, const float* __restrict__ b5,
                 const float* __restrict__ fcw, const float* __restrict__ fcb,
                 float* __restrict__ out)
{
    const int n = blockIdx.x;
    const int t = threadIdx.x;
    const int e = t & (EE - 1);
    const int half = t >> 7;

    __shared__ float docT[EE][LL + 2];       // transposed doc tile, 2 zero rows pad
    __shared__ float feats[3 * CC];
    __shared__ int rows[LL];

    if (t < LL) rows[t] = news_words[n * LL + t];
    __syncthreads();
    for (int l = half; l < LL; l += 2) docT[e][l] = we[rows[l] * EE + e];
    docT[e][LL + half] = 0.0f;               // pad rows 64,65
    __syncthreads();

    const int c = e;
    conv_one<3>(docT, w3, b3, c, half, feats + 0 * CC);
    conv_one<4>(docT, w4, b4, c, half, feats + 1 * CC);
    conv_one<5>(docT, w5, b5, c, half, feats + 2 * CC);

    // fc: out[n, i] = fc_b[i] + sum_f feats[f] * fc_w[i, f]
    if (t < EE) {
        float acc = fcb[t];
        const float* wr = fcw + t * (3 * CC);
        for (int f = 0; f < 3 * CC; ++f) acc += feats[f] * wr[f];
        out[n * EE + t] = acc;
    }
}

// ---------------------------------------------------------------------------
extern "C" void kernel_launch(void* const* d_in, const int* in_sizes, int n_in,
                              void* d_out, int out_size, void* d_ws, size_t ws_size,
                              hipStream_t stream)
{
    const int*   word2news     = (const int*)d_in[0];
    const int*   word2news_len = (const int*)d_in[1];
    const int*   news_words    = (const int*)d_in[2];
    const float* table         = (const float*)d_in[3];
    const float* in_w          = (const float*)d_in[4];
    const float* in_b          = (const float*)d_in[5];
    const float* out_w         = (const float*)d_in[6];
    const float* out_b         = (const float*)d_in[7];
    const float* w3            = (const float*)d_in[8];
    const float* b3            = (const float*)d_in[9];
    const float* w4            = (const float*)d_in[10];
    const float* b4            = (const float*)d_in[11];
    const float* w5            = (const float*)d_in[12];
    const float* b5            = (const float*)d_in[13];
    const float* fcw           = (const float*)d_in[14];
    const float* fcb           = (const float*)d_in[15];

    float* out = (float*)d_out;
    float* we  = (float*)d_ws;               // [V_WORDS, EE] fp32 = 10.24 MB

    word_embed_kernel<<<V_WORDS, 256, 0, stream>>>(
        word2news, word2news_len, table, in_w, in_b, out_w, out_b, we);
    news_kernel<<<NN, 256, 0, stream>>>(
        news_words, we, w3, b3, w4, b4, w5, b5, fcw, fcb, out);
}

// Round 2
// 1939.830 us; speedup vs baseline: 2.3892x; 2.3892x over previous
//
#include <hip/hip_runtime.h>
#include <math.h>

#define V_WORDS 20000
#define MM 32
#define EE 128
#define HH 4
#define DHH 32
#define NN 8192
#define LL 64
#define CC 128

typedef short bf16x8 __attribute__((ext_vector_type(8)));
typedef float f32x4 __attribute__((ext_vector_type(4)));
typedef unsigned short u16;
typedef unsigned int u32;

// fp32 -> bf16 round-to-nearest-even (finite inputs only)
__device__ __forceinline__ u16 f2bf(float x) {
    u32 u = __float_as_uint(x);
    u32 r = (u + 0x7FFFu + ((u >> 16) & 1u)) >> 16;
    return (u16)r;
}

// ---------------------------------------------------------------------------
// Kernel 0: pack conv weights into bf16 MFMA B-fragment order.
// Bpack[slice][ntile][lane][i] , slice = (conv, j, e0/32), i = 0..7
//   value = w_conv[c = nt*16 + (lane&15)][e = e0 + (lane>>4)*8 + i][j]
// 48 slices: conv3 s=0..11, conv4 s=12..27, conv5 s=28..47; s'=j*4+eblk
// ---------------------------------------------------------------------------
__global__ __launch_bounds__(256)
void pack_weights(const float* __restrict__ w3,
                  const float* __restrict__ w4,
                  const float* __restrict__ w5,
                  u16* __restrict__ Bpack)
{
    const int s = blockIdx.x;
    const int t = threadIdx.x;
    const int lane = t & 63;

    const float* src;
    int K, sl;
    if (s < 12)      { src = w3; K = 3; sl = s; }
    else if (s < 28) { src = w4; K = 4; sl = s - 12; }
    else             { src = w5; K = 5; sl = s - 28; }
    const int j  = sl >> 2;
    const int e0 = (sl & 3) * 32;

    for (int nt = (t >> 6); nt < 8; nt += 4) {
        const int c = nt * 16 + (lane & 15);
        const int kb = (lane >> 4) * 8;
        u16 vals[8];
        #pragma unroll
        for (int i = 0; i < 8; ++i) {
            const int e = e0 + kb + i;
            vals[i] = f2bf(src[(c * EE + e) * K + j]);
        }
        u16* dst = Bpack + (((size_t)s * 8 + nt) * 64 + lane) * 8;
        *(bf16x8*)dst = *(const bf16x8*)vals;
    }
}

// ---------------------------------------------------------------------------
// Kernel 1: word embeddings (masked mean query + 1-query MHA + out proj)
// one block per word, 256 threads.  Output: bf16 table we16[V][E].
// ---------------------------------------------------------------------------
__global__ __launch_bounds__(256)
void word_embed_kernel(const int* __restrict__ word2news,
                       const int* __restrict__ word2news_len,
                       const float* __restrict__ table,
                       const float* __restrict__ in_w,
                       const float* __restrict__ in_b,
                       const float* __restrict__ out_w,
                       const float* __restrict__ out_b,
                       u16* __restrict__ we16)
{
    const int v = blockIdx.x;
    const int t = threadIdx.x;
    const int len = word2news_len[v];
    if (len <= 0) {                       // reference zeroes words with no news
        if (t < EE) we16[v * EE + t] = 0;
        return;
    }

    __shared__ float ctx[MM][EE];
    __shared__ float khs[MM][EE];
    __shared__ float vhs[MM][EE];
    __shared__ float qs[EE];
    __shared__ float qhs[EE];
    __shared__ float attn[HH][MM];
    __shared__ float osh[EE];
    __shared__ int rows[MM];

    const int e = t & (EE - 1);
    const int hpart = t >> 7;             // 0 or 1

    if (t < MM) rows[t] = word2news[v * MM + t];
    __syncthreads();

    for (int m = hpart; m < MM; m += 2) {
        float val = 0.0f;
        if (m < len) val = table[rows[m] * EE + e];
        ctx[m][e] = val;
    }
    __syncthreads();

    if (t < EE) {
        float s = 0.0f;
        #pragma unroll
        for (int m = 0; m < MM; ++m) s += ctx[m][t];
        qs[t] = s / (float)len;
    }
    __syncthreads();

    if (t < EE) {
        float acc = in_b[t];
        const float* wq = in_w + t * EE;
        for (int k = 0; k < EE; ++k) acc += qs[k] * wq[k];
        qhs[t] = acc;
    }

    {
        const int i = e;
        const float* w = in_w + (hpart == 0 ? EE * EE : 2 * EE * EE) + i * EE;
        const float bias = in_b[(hpart == 0 ? EE : 2 * EE) + i];
        float (*dst)[EE] = (hpart == 0) ? khs : vhs;

        float acc[16];
        #pragma unroll
        for (int m = 0; m < 16; ++m) acc[m] = bias;
        for (int k = 0; k < EE; ++k) {
            const float wv = w[k];
            #pragma unroll
            for (int m = 0; m < 16; ++m) acc[m] += ctx[m][k] * wv;
        }
        #pragma unroll
        for (int m = 0; m < 16; ++m) dst[m][i] = acc[m];

        if (len > 16) {
            #pragma unroll
            for (int m = 0; m < 16; ++m) acc[m] = bias;
            for (int k = 0; k < EE; ++k) {
                const float wv = w[k];
                #pragma unroll
                for (int m = 0; m < 16; ++m) acc[m] += ctx[16 + m][k] * wv;
            }
            #pragma unroll
            for (int m = 0; m < 16; ++m) dst[16 + m][i] = acc[m];
        } else {
            #pragma unroll
            for (int m = 16; m < MM; ++m) dst[m][i] = 0.0f;
        }
    }
    __syncthreads();

    if (t < HH * MM) {
        const int h = t >> 5, m = t & 31;
        float s;
        if (m < len) {
            float d = 0.0f;
            #pragma unroll
            for (int dd = 0; dd < DHH; ++dd)
                d += qhs[h * DHH + dd] * khs[m][h * DHH + dd];
            s = d * 0.17677669529663687f;   // 1/sqrt(Dh)
        } else {
            s = -1e9f;
        }
        float mx = s;
        #pragma unroll
        for (int off = 16; off > 0; off >>= 1)
            mx = fmaxf(mx, __shfl_xor(mx, off, 32));
        const float ex = expf(s - mx);
        float sum = ex;
        #pragma unroll
        for (int off = 16; off > 0; off >>= 1)
            sum += __shfl_xor(sum, off, 32);
        attn[h][m] = ex / sum;
    }
    __syncthreads();

    if (t < EE) {
        const int h = t >> 5;
        float acc = 0.0f;
        #pragma unroll
        for (int m = 0; m < MM; ++m) acc += attn[h][m] * vhs[m][t];
        osh[t] = acc;
    }
    __syncthreads();

    if (t < EE) {
        float acc = out_b[t];
        const float* wr = out_w + t * EE;
        for (int k = 0; k < EE; ++k) acc += osh[k] * wr[k];
        we16[v * EE + t] = f2bf(acc);
    }
}

// ---------------------------------------------------------------------------
// Kernel 2: implicit-GEMM conv via bf16 MFMA.
// One block per news item, 256 threads = 4 waves.
// doc tile in LDS: [68 rows][136 bf16] (stride 136 = +16B pad -> 2-way banks)
// wave w owns N-tiles {2w, 2w+1} (channels 32w..32w+31), all 4 M-tiles.
// A frag: lane holds doc[16*mt + (l&15) + j][e0 + (l>>4)*8 + i]  (ds_read_b128)
// B frag: from Bpack, lane-contiguous 16B (global_load_dwordx4, L2-resident)
// D frag: p = 16*mt + (l>>4)*4 + r, c = 32w + nt*16 + (l&15)
// ---------------------------------------------------------------------------
#define DSTRIDE 136
#define DROWS   68

template<int NSL, int SBASE, int NP, int KOFF>
__device__ __forceinline__ void conv_mfma(const u16* __restrict__ doc,
                                          const u16* __restrict__ Bpack,
                                          const float* __restrict__ bk,
                                          float* __restrict__ feats,
                                          int w, int l)
{
    f32x4 acc[4][2];
    #pragma unroll
    for (int mt = 0; mt < 4; ++mt)
        #pragma unroll
        for (int nt = 0; nt < 2; ++nt)
            acc[mt][nt] = (f32x4){0.f, 0.f, 0.f, 0.f};

    const u16* bbase = Bpack + (size_t)SBASE * 4096 + (w * 2) * 512 + l * 8;
    const int lm = l & 15;
    const int col = (l >> 4) * 8;

    for (int s = 0; s < NSL; ++s) {
        const int j  = s >> 2;
        const int e0 = (s & 3) * 32;
        const bf16x8 b0 = *(const bf16x8*)(bbase + s * 4096);
        const bf16x8 b1 = *(const bf16x8*)(bbase + s * 4096 + 512);
        const u16* arow = doc + (lm + j) * DSTRIDE + e0 + col;
        bf16x8 a[4];
        #pragma unroll
        for (int mt = 0; mt < 4; ++mt)
            a[mt] = *(const bf16x8*)(arow + mt * (16 * DSTRIDE));
        #pragma unroll
        for (int mt = 0; mt < 4; ++mt) {
            acc[mt][0] = __builtin_amdgcn_mfma_f32_16x16x32_bf16(a[mt], b0, acc[mt][0], 0, 0, 0);
            acc[mt][1] = __builtin_amdgcn_mfma_f32_16x16x32_bf16(a[mt], b1, acc[mt][1], 0, 0, 0);
        }
    }

    // epilogue: +bias, relu, masked max over positions, reduce across lanes
    #pragma unroll
    for (int nt = 0; nt < 2; ++nt) {
        const int c = w * 32 + nt * 16 + lm;
        const float bias = bk[c];
        float mx = 0.0f;                       // relu output >= 0
        #pragma unroll
        for (int mt = 0; mt < 4; ++mt) {
            #pragma unroll
            for (int r = 0; r < 4; ++r) {
                const int p = 16 * mt + (l >> 4) * 4 + r;
                const float y = fmaxf(acc[mt][nt][r] + bias, 0.0f);
                if (p < NP) mx = fmaxf(mx, y);
            }
        }
        mx = fmaxf(mx, __shfl_xor(mx, 16));
        mx = fmaxf(mx, __shfl_xor(mx, 32));
        if ((l >> 4) == 0) feats[KOFF + c] = mx;
    }
}

__global__ __launch_bounds__(256)
void news_kernel(const int* __restrict__ news_words,
                 const u16* __restrict__ we16,
                 const u16* __restrict__ Bpack,
                 const float* __restrict__ b3,
                 const float* __restrict__ b4,
                 const float* __restrict__ b5,
                 const float* __restrict__ fcw, const float* __restrict__ fcb,
                 float* __restrict__ out)
{
    const int n = blockIdx.x;
    const int t = threadIdx.x;
    const int w = t >> 6;
    const int l = t & 63;

    __shared__ u16 doc[DROWS * DSTRIDE];
    __shared__ float feats[3 * CC];
    __shared__ int rows[LL];

    if (t < LL) rows[t] = news_words[n * LL + t];
    __syncthreads();

    // gather 64 doc rows (bf16, 64 uints each) + zero-pad rows 64..67
    {
        const u32* weU = (const u32*)we16;
        u32* docU = (u32*)doc;
        for (int idx = t; idx < 4096 + 4 * 64; idx += 256) {
            if (idx < 4096) {
                const int row = idx >> 6, c2 = idx & 63;
                docU[row * 68 + c2] = weU[(size_t)rows[row] * 64 + c2];
            } else {
                const int k = idx - 4096;
                docU[(64 + (k >> 6)) * 68 + (k & 63)] = 0u;
            }
        }
    }
    __syncthreads();

    conv_mfma<12,  0, 62, 0 * CC>(doc, Bpack, b3, feats, w, l);
    conv_mfma<16, 12, 61, 1 * CC>(doc, Bpack, b4, feats, w, l);
    conv_mfma<20, 28, 60, 2 * CC>(doc, Bpack, b5, feats, w, l);
    __syncthreads();

    // fc: out[n, i] = fc_b[i] + sum_f feats[f] * fc_w[i, f]   (fp32)
    if (t < EE) {
        float acc = fcb[t];
        const float* wr = fcw + t * (3 * CC);
        for (int f = 0; f < 3 * CC; ++f) acc += feats[f] * wr[f];
        out[n * EE + t] = acc;
    }
}

// ---------------------------------------------------------------------------
extern "C" void kernel_launch(void* const* d_in, const int* in_sizes, int n_in,
                              void* d_out, int out_size, void* d_ws, size_t ws_size,
                              hipStream_t stream)
{
    const int*   word2news     = (const int*)d_in[0];
    const int*   word2news_len = (const int*)d_in[1];
    const int*   news_words    = (const int*)d_in[2];
    const float* table         = (const float*)d_in[3];
    const float* in_w          = (const float*)d_in[4];
    const float* in_b          = (const float*)d_in[5];
    const float* out_w         = (const float*)d_in[6];
    const float* out_b         = (const float*)d_in[7];
    const float* w3            = (const float*)d_in[8];
    const float* b3            = (const float*)d_in[9];
    const float* w4            = (const float*)d_in[10];
    const float* b4            = (const float*)d_in[11];
    const float* w5            = (const float*)d_in[12];
    const float* b5            = (const float*)d_in[13];
    const float* fcw           = (const float*)d_in[14];
    const float* fcb           = (const float*)d_in[15];

    float* out = (float*)d_out;
    u16* we16  = (u16*)d_ws;                          // [V,E] bf16 = 5.12 MB
    u16* Bpack = (u16*)((char*)d_ws + (size_t)V_WORDS * EE * 2);  // 393 KB

    pack_weights<<<48, 256, 0, stream>>>(w3, w4, w5, Bpack);
    word_embed_kernel<<<V_WORDS, 256, 0, stream>>>(
        word2news, word2news_len, table, in_w, in_b, out_w, out_b, we16);
    news_kernel<<<NN, 256, 0, stream>>>(
        news_words, we16, Bpack, b3, b4, b5, fcw, fcb, out);
}

// Round 3
// 911.319 us; speedup vs baseline: 5.0857x; 2.1286x over previous
//
#include <hip/hip_runtime.h>
#include <math.h>

#define V_WORDS 20000
#define MM 32
#define EE 128
#define HH 4
#define DHH 32
#define NN 8192
#define LL 64
#define CC 128

typedef short bf16x8 __attribute__((ext_vector_type(8)));
typedef float f32x4 __attribute__((ext_vector_type(4)));
typedef unsigned short u16;
typedef unsigned int u32;

__device__ __forceinline__ u16 f2bf(float x) {
    u32 u = __float_as_uint(x);
    u32 r = (u + 0x7FFFu + ((u >> 16) & 1u)) >> 16;
    return (u16)r;
}
__device__ __forceinline__ float bflo(u32 u) { return __uint_as_float(u << 16); }
__device__ __forceinline__ float bfhi(u32 u) { return __uint_as_float(u & 0xFFFF0000u); }

// ---------------------------------------------------------------------------
// Kernel 0: pack conv weights into bf16 MFMA B-fragment order (unchanged R2).
// ---------------------------------------------------------------------------
__global__ __launch_bounds__(256)
void pack_weights(const float* __restrict__ w3,
                  const float* __restrict__ w4,
                  const float* __restrict__ w5,
                  u16* __restrict__ Bpack)
{
    const int s = blockIdx.x;
    const int t = threadIdx.x;
    const int lane = t & 63;

    const float* src;
    int K, sl;
    if (s < 12)      { src = w3; K = 3; sl = s; }
    else if (s < 28) { src = w4; K = 4; sl = s - 12; }
    else             { src = w5; K = 5; sl = s - 28; }
    const int j  = sl >> 2;
    const int e0 = (sl & 3) * 32;

    for (int nt = (t >> 6); nt < 8; nt += 4) {
        const int c = nt * 16 + (lane & 15);
        const int kb = (lane >> 4) * 8;
        u16 vals[8];
        #pragma unroll
        for (int i = 0; i < 8; ++i) {
            const int e = e0 + kb + i;
            vals[i] = f2bf(src[(c * EE + e) * K + j]);
        }
        u16* dst = Bpack + (((size_t)s * 8 + nt) * 64 + lane) * 8;
        *(bf16x8*)dst = *(const bf16x8*)vals;
    }
}

// ---------------------------------------------------------------------------
// Kernel A: Kn = table @ wk^T + bk, Vn = table @ wv^T + bv  (bf16 out)
// 8 news rows per block; 256 threads = {K,V} x 128 dims.
// Exploits: only N=8192 distinct rows ever get k/v-projected (vs V*M=640k).
// ---------------------------------------------------------------------------
__global__ __launch_bounds__(256)
void kv_proj_kernel(const float* __restrict__ table,
                    const float* __restrict__ in_w,
                    const float* __restrict__ in_b,
                    u16* __restrict__ Kn16, u16* __restrict__ Vn16)
{
    const int n0 = blockIdx.x * 8;
    const int t = threadIdx.x;
    __shared__ float tbl[8][EE];
    {
        const int r = t >> 5, q4 = (t & 31) * 4;
        *(float4*)&tbl[r][q4] = *(const float4*)&table[(size_t)(n0 + r) * EE + q4];
    }
    __syncthreads();

    const int sel = t >> 7;                 // 0 = K, 1 = V
    const int i = t & 127;
    const float* w = in_w + (size_t)(sel + 1) * EE * EE + (size_t)i * EE;
    const float bias = in_b[(sel + 1) * EE + i];

    float acc[8];
    #pragma unroll
    for (int r = 0; r < 8; ++r) acc[r] = bias;
    for (int k = 0; k < EE; k += 4) {
        const float4 wv = *(const float4*)&w[k];
        #pragma unroll
        for (int r = 0; r < 8; ++r) {
            acc[r] += tbl[r][k]     * wv.x + tbl[r][k + 1] * wv.y
                    + tbl[r][k + 2] * wv.z + tbl[r][k + 3] * wv.w;
        }
    }
    u16* dst = sel ? Vn16 : Kn16;
    #pragma unroll
    for (int r = 0; r < 8; ++r) dst[(size_t)(n0 + r) * EE + i] = f2bf(acc[r]);
}

// ---------------------------------------------------------------------------
// Kernel B: per-word attention using gathered Kn/Vn. 8 words per block.
// ---------------------------------------------------------------------------
#define WPB 8
__global__ __launch_bounds__(256)
void word_attn_kernel(const int* __restrict__ word2news,
                      const int* __restrict__ word2news_len,
                      const float* __restrict__ table,
                      const float* __restrict__ in_w,
                      const float* __restrict__ in_b,
                      const float* __restrict__ out_w,
                      const float* __restrict__ out_b,
                      const u16* __restrict__ Kn16,
                      const u16* __restrict__ Vn16,
                      u16* __restrict__ we16)
{
    const int v0 = blockIdx.x * WPB;
    const int t = threadIdx.x;

    __shared__ int   rows[WPB][MM];
    __shared__ int   lenS[WPB];
    __shared__ float q[WPB][EE];
    __shared__ float qh[WPB][EE];
    __shared__ float attn[WPB][HH][MM];
    __shared__ float osh[WPB][EE];

    {
        const int w = t >> 5, m = t & 31;
        rows[w][m] = word2news[(size_t)(v0 + w) * MM + m];
        if (t < WPB) lenS[t] = word2news_len[v0 + t];
    }
    __syncthreads();

    // q = masked mean of table rows
    {
        const int w = t >> 5, d0 = (t & 31) * 4;
        const int L = lenS[w];
        float4 a = {0.f, 0.f, 0.f, 0.f};
        for (int m = 0; m < L; ++m) {
            const float4 x = *(const float4*)&table[(size_t)rows[w][m] * EE + d0];
            a.x += x.x; a.y += x.y; a.z += x.z; a.w += x.w;
        }
        const float inv = (L > 0) ? 1.0f / (float)L : 0.0f;
        a.x *= inv; a.y *= inv; a.z *= inv; a.w *= inv;
        *(float4*)&q[w][d0] = a;
    }
    __syncthreads();

    // qh = q @ wq^T + bq  (weight row reused for 4 words)
    {
        const int g = t >> 7, i = t & 127;
        const float* wr = in_w + (size_t)i * EE;
        float acc[4] = {0.f, 0.f, 0.f, 0.f};
        for (int k = 0; k < EE; k += 4) {
            const float4 wv = *(const float4*)&wr[k];
            #pragma unroll
            for (int w4 = 0; w4 < 4; ++w4) {
                const float* qw = q[g * 4 + w4];
                acc[w4] += qw[k] * wv.x + qw[k + 1] * wv.y
                         + qw[k + 2] * wv.z + qw[k + 3] * wv.w;
            }
        }
        const float b = in_b[i];
        #pragma unroll
        for (int w4 = 0; w4 < 4; ++w4) qh[g * 4 + w4][i] = acc[w4] + b;
    }
    __syncthreads();

    // scores (gather Kn rows) + softmax over m (width-32 shuffles)
    {
        const int w = t >> 5, m = t & 31;
        const int L = lenS[w];
        float s[HH] = {-1e9f, -1e9f, -1e9f, -1e9f};
        if (m < L) {
            const uint4* kr = (const uint4*)(Kn16 + (size_t)rows[w][m] * EE);
            #pragma unroll
            for (int h = 0; h < HH; ++h) {
                float a = 0.f;
                #pragma unroll
                for (int k8 = 0; k8 < 4; ++k8) {
                    const uint4 u = kr[h * 4 + k8];
                    const float4 q0 = *(const float4*)&qh[w][h * 32 + k8 * 8];
                    const float4 q1 = *(const float4*)&qh[w][h * 32 + k8 * 8 + 4];
                    a += q0.x * bflo(u.x) + q0.y * bfhi(u.x)
                       + q0.z * bflo(u.y) + q0.w * bfhi(u.y)
                       + q1.x * bflo(u.z) + q1.y * bfhi(u.z)
                       + q1.z * bflo(u.w) + q1.w * bfhi(u.w);
                }
                s[h] = a * 0.17677669529663687f;   // 1/sqrt(Dh)
            }
        }
        #pragma unroll
        for (int h = 0; h < HH; ++h) {
            float mx = s[h];
            #pragma unroll
            for (int off = 16; off > 0; off >>= 1)
                mx = fmaxf(mx, __shfl_xor(mx, off, 32));
            const float ex = expf(s[h] - mx);      // masked lanes underflow to 0
            float sum = ex;
            #pragma unroll
            for (int off = 16; off > 0; off >>= 1)
                sum += __shfl_xor(sum, off, 32);
            attn[w][h][m] = ex / sum;
        }
    }
    __syncthreads();

    // o = attn-weighted sum of Vn rows
    {
        const int w = t >> 5, d0 = (t & 31) * 4;
        const int L = lenS[w];
        const int h = d0 >> 5;
        float4 a = {0.f, 0.f, 0.f, 0.f};
        for (int m = 0; m < L; ++m) {
            const float aw = attn[w][h][m];
            const u32* vr = (const u32*)(Vn16 + (size_t)rows[w][m] * EE + d0);
            const u32 u0 = vr[0], u1 = vr[1];
            a.x += aw * bflo(u0); a.y += aw * bfhi(u0);
            a.z += aw * bflo(u1); a.w += aw * bfhi(u1);
        }
        *(float4*)&osh[w][d0] = a;
    }
    __syncthreads();

    // out proj + bf16 store (zero for len==0 words, matching reference)
    {
        const int g = t >> 7, i = t & 127;
        const float* wr = out_w + (size_t)i * EE;
        float acc[4] = {0.f, 0.f, 0.f, 0.f};
        for (int k = 0; k < EE; k += 4) {
            const float4 wv = *(const float4*)&wr[k];
            #pragma unroll
            for (int w4 = 0; w4 < 4; ++w4) {
                const float* ow = osh[g * 4 + w4];
                acc[w4] += ow[k] * wv.x + ow[k + 1] * wv.y
                         + ow[k + 2] * wv.z + ow[k + 3] * wv.w;
            }
        }
        const float b = out_b[i];
        #pragma unroll
        for (int w4 = 0; w4 < 4; ++w4) {
            const int w = g * 4 + w4;
            we16[(size_t)(v0 + w) * EE + i] =
                (lenS[w] > 0) ? f2bf(acc[w4] + b) : (u16)0;
        }
    }
}

// ---------------------------------------------------------------------------
// Kernel 2: implicit-GEMM conv via bf16 MFMA (unchanged from R2).
// ---------------------------------------------------------------------------
#define DSTRIDE 136
#define DROWS   68

template<int NSL, int SBASE, int NP, int KOFF>
__device__ __forceinline__ void conv_mfma(const u16* __restrict__ doc,
                                          const u16* __restrict__ Bpack,
                                          const float* __restrict__ bk,
                                          float* __restrict__ feats,
                                          int w, int l)
{
    f32x4 acc[4][2];
    #pragma unroll
    for (int mt = 0; mt < 4; ++mt)
        #pragma unroll
        for (int nt = 0; nt < 2; ++nt)
            acc[mt][nt] = (f32x4){0.f, 0.f, 0.f, 0.f};

    const u16* bbase = Bpack + (size_t)SBASE * 4096 + (w * 2) * 512 + l * 8;
    const int lm = l & 15;
    const int col = (l >> 4) * 8;

    for (int s = 0; s < NSL; ++s) {
        const int j  = s >> 2;
        const int e0 = (s & 3) * 32;
        const bf16x8 b0 = *(const bf16x8*)(bbase + s * 4096);
        const bf16x8 b1 = *(const bf16x8*)(bbase + s * 4096 + 512);
        const u16* arow = doc + (lm + j) * DSTRIDE + e0 + col;
        bf16x8 a[4];
        #pragma unroll
        for (int mt = 0; mt < 4; ++mt)
            a[mt] = *(const bf16x8*)(arow + mt * (16 * DSTRIDE));
        #pragma unroll
        for (int mt = 0; mt < 4; ++mt) {
            acc[mt][0] = __builtin_amdgcn_mfma_f32_16x16x32_bf16(a[mt], b0, acc[mt][0], 0, 0, 0);
            acc[mt][1] = __builtin_amdgcn_mfma_f32_16x16x32_bf16(a[mt], b1, acc[mt][1], 0, 0, 0);
        }
    }

    #pragma unroll
    for (int nt = 0; nt < 2; ++nt) {
        const int c = w * 32 + nt * 16 + lm;
        const float bias = bk[c];
        float mx = 0.0f;
        #pragma unroll
        for (int mt = 0; mt < 4; ++mt) {
            #pragma unroll
            for (int r = 0; r < 4; ++r) {
                const int p = 16 * mt + (l >> 4) * 4 + r;
                const float y = fmaxf(acc[mt][nt][r] + bias, 0.0f);
                if (p < NP) mx = fmaxf(mx, y);
            }
        }
        mx = fmaxf(mx, __shfl_xor(mx, 16));
        mx = fmaxf(mx, __shfl_xor(mx, 32));
        if ((l >> 4) == 0) feats[KOFF + c] = mx;
    }
}

__global__ __launch_bounds__(256)
void news_kernel(const int* __restrict__ news_words,
                 const u16* __restrict__ we16,
                 const u16* __restrict__ Bpack,
                 const float* __restrict__ b3,
                 const float* __restrict__ b4,
                 const float* __restrict__ b5,
                 const float* __restrict__ fcw, const float* __restrict__ fcb,
                 float* __restrict__ out)
{
    const int n = blockIdx.x;
    const int t = threadIdx.x;
    const int w = t >> 6;
    const int l = t & 63;

    __shared__ u16 doc[DROWS * DSTRIDE];
    __shared__ float feats[3 * CC];
    __shared__ int rows[LL];

    if (t < LL) rows[t] = news_words[n * LL + t];
    __syncthreads();

    {
        const u32* weU = (const u32*)we16;
        u32* docU = (u32*)doc;
        for (int idx = t; idx < 4096 + 4 * 64; idx += 256) {
            if (idx < 4096) {
                const int row = idx >> 6, c2 = idx & 63;
                docU[row * 68 + c2] = weU[(size_t)rows[row] * 64 + c2];
            } else {
                const int k = idx - 4096;
                docU[(64 + (k >> 6)) * 68 + (k & 63)] = 0u;
            }
        }
    }
    __syncthreads();

    conv_mfma<12,  0, 62, 0 * CC>(doc, Bpack, b3, feats, w, l);
    conv_mfma<16, 12, 61, 1 * CC>(doc, Bpack, b4, feats, w, l);
    conv_mfma<20, 28, 60, 2 * CC>(doc, Bpack, b5, feats, w, l);
    __syncthreads();

    if (t < EE) {
        float acc = fcb[t];
        const float* wr = fcw + t * (3 * CC);
        for (int f = 0; f < 3 * CC; ++f) acc += feats[f] * wr[f];
        out[n * EE + t] = acc;
    }
}

// ---------------------------------------------------------------------------
extern "C" void kernel_launch(void* const* d_in, const int* in_sizes, int n_in,
                              void* d_out, int out_size, void* d_ws, size_t ws_size,
                              hipStream_t stream)
{
    const int*   word2news     = (const int*)d_in[0];
    const int*   word2news_len = (const int*)d_in[1];
    const int*   news_words    = (const int*)d_in[2];
    const float* table         = (const float*)d_in[3];
    const float* in_w          = (const float*)d_in[4];
    const float* in_b          = (const float*)d_in[5];
    const float* out_w         = (const float*)d_in[6];
    const float* out_b         = (const float*)d_in[7];
    const float* w3            = (const float*)d_in[8];
    const float* b3            = (const float*)d_in[9];
    const float* w4            = (const float*)d_in[10];
    const float* b4            = (const float*)d_in[11];
    const float* w5            = (const float*)d_in[12];
    const float* b5            = (const float*)d_in[13];
    const float* fcw           = (const float*)d_in[14];
    const float* fcb           = (const float*)d_in[15];

    float* out = (float*)d_out;
    u16* base  = (u16*)d_ws;
    u16* we16  = base;                                   // 2,560,000 u16 (5.12 MB)
    u16* Bpack = base + 2560000;                         //   196,608 u16 (0.39 MB)
    u16* Kn16  = base + 2756608;                         // 1,048,576 u16 (2.10 MB)
    u16* Vn16  = base + 3805184;                         // 1,048,576 u16 (2.10 MB)
                                                         // total 9.71 MB (< R1's 10.24)

    pack_weights<<<48, 256, 0, stream>>>(w3, w4, w5, Bpack);
    kv_proj_kernel<<<NN / 8, 256, 0, stream>>>(table, in_w, in_b, Kn16, Vn16);
    word_attn_kernel<<<V_WORDS / WPB, 256, 0, stream>>>(
        word2news, word2news_len, table, in_w, in_b, out_w, out_b,
        Kn16, Vn16, we16);
    news_kernel<<<NN, 256, 0, stream>>>(
        news_words, we16, Bpack, b3, b4, b5, fcw, fcb, out);
}